// Round 1
// baseline (335.568 us; speedup 1.0000x reference)
//
#include <hip/hip_runtime.h>

namespace {
constexpr int CC = 3, FF = 51;
constexpr int HOUT = 384, WOUT = 384;
constexpr int HIN = 434, WIN = 434;
constexpr int KY = 4;               // vertical outputs per thread
constexpr int TX = 128;             // block width (threads)
constexpr int EXT = 180;            // staged f16 elems per channel row
constexpr int LPAD = 184;           // LDS row pitch (f16), keeps 8B alignment
constexpr int NPAIR = 28;           // f16 pairs per horizontal dot
constexpr int NQ = NPAIR / 2;       // 8-byte LDS reads per dot (14)
constexpr int NSTEP = FF + KY - 1;  // 54 input rows per tile
constexpr int NSG = (CC * EXT + TX - 1) / TX;  // staging loads/thread (5)

using half2v = _Float16 __attribute__((ext_vector_type(2)));

__device__ __forceinline__ float fdot2f(half2v a, half2v b, float c) {
#if __has_builtin(__builtin_amdgcn_fdot2)
  return __builtin_amdgcn_fdot2(a, b, c, false);
#else
  return c + (float)a.x * (float)b.x + (float)a.y * (float)b.y;
#endif
}
}  // namespace

__global__ __launch_bounds__(TX, 2) void sepconv_kernel(
    const float* __restrict__ In, const float* __restrict__ Ver,
    const float* __restrict__ Hor, float* __restrict__ Out) {
  const int tid = threadIdx.x;
  const int x0 = blockIdx.x * TX;
  const int y0 = blockIdx.y * KY;
  const int b = blockIdx.z;
  const int x = x0 + tid;
  const int a = tid & 3;        // alignment class (f16 elems)
  const int base4 = tid - a;    // 8B-aligned local window base

  __shared__ __align__(16) unsigned short sIn[2][CC][LPAD];

  const size_t HW = (size_t)HOUT * WOUT;

  // ---- pack per-pixel horizontal taps: hp[t][j] = (h[2j-a], h[2j-a+1]), OOB->0
  half2v hp[KY][NPAIR];
  {
    const float* horx = Hor + (size_t)b * FF * HW + x;
#pragma unroll
    for (int t = 0; t < KY; ++t) {
      const float* hb = horx + (size_t)(y0 + t) * WOUT;
#pragma unroll
      for (int j = 0; j < NPAIR; ++j) {
        const int lo = 2 * j - a;
        const int hi = lo + 1;
        float flo = (lo >= 0 && lo < FF)
                        ? __builtin_nontemporal_load(&hb[(size_t)lo * HW])
                        : 0.0f;
        float fhi = (hi >= 0 && hi < FF)
                        ? __builtin_nontemporal_load(&hb[(size_t)hi * HW])
                        : 0.0f;
        auto pk = __builtin_amdgcn_cvt_pkrtz(flo, fhi);
        hp[t][j] = __builtin_bit_cast(half2v, pk);
      }
    }
  }

  const float* inb = In + (size_t)b * CC * HIN * WIN + x0;
  const float* verb = Ver + (size_t)b * FF * HW + (size_t)y0 * WOUT + x;

  // ---- prologue: stage input row y0 into buffer 0 (f32 -> f16)
#pragma unroll
  for (int k = 0; k < NSG; ++k) {
    const int idx = tid + k * TX;
    if (idx < CC * EXT) {
      const int c = idx / EXT;
      const int e = idx - c * EXT;
      float v = 0.0f;
      if (x0 + e < WIN) v = inb[(size_t)(c * HIN + y0) * WIN + e];
      sIn[0][c][e] = __builtin_bit_cast(unsigned short, (_Float16)v);
    }
  }
  __syncthreads();

  float acc[CC][KY] = {};

  for (int r = 0; r < NSTEP; ++r) {
    const int buf = r & 1;
    const bool more = (r + 1 < NSTEP);

    // T14: issue next-row global loads before compute
    float sv[NSG];
    if (more) {
#pragma unroll
      for (int k = 0; k < NSG; ++k) {
        const int idx = tid + k * TX;
        sv[k] = 0.0f;
        if (idx < CC * EXT) {
          const int c = idx / EXT;
          const int e = idx - c * EXT;
          if (x0 + e < WIN)
            sv[k] = inb[(size_t)(c * HIN + (y0 + r + 1)) * WIN + e];
        }
      }
    }

    // per-row vertical weights (0 outside valid fy range -> branchless accumulate)
    float vv[KY];
#pragma unroll
    for (int t = 0; t < KY; ++t) {
      const int fy = r - t;
      vv[t] = (fy >= 0 && fy < FF)
                  ? __builtin_nontemporal_load(&verb[(size_t)fy * HW + t * WOUT])
                  : 0.0f;
    }

    // horizontal dots from LDS (ds_read_b64, 4 f16 each), KY-way register reuse
#pragma unroll
    for (int c = 0; c < CC; ++c) {
      const unsigned short* rp = &sIn[buf][c][base4];
      float d[KY] = {};
#pragma unroll
      for (int q = 0; q < NQ; ++q) {
        const uint2 u2 = *reinterpret_cast<const uint2*>(rp + 4 * q);
        const half2v p0 = __builtin_bit_cast(half2v, u2.x);
        const half2v p1 = __builtin_bit_cast(half2v, u2.y);
#pragma unroll
        for (int t = 0; t < KY; ++t) {
          d[t] = fdot2f(p0, hp[t][2 * q], d[t]);
          d[t] = fdot2f(p1, hp[t][2 * q + 1], d[t]);
        }
      }
#pragma unroll
      for (int t = 0; t < KY; ++t) acc[c][t] += d[t] * vv[t];
    }

    // write staged row for r+1 into the other buffer, then one barrier/step
    if (more) {
#pragma unroll
      for (int k = 0; k < NSG; ++k) {
        const int idx = tid + k * TX;
        if (idx < CC * EXT) {
          const int c = idx / EXT;
          const int e = idx - c * EXT;
          sIn[buf ^ 1][c][e] = __builtin_bit_cast(unsigned short, (_Float16)sv[k]);
        }
      }
    }
    __syncthreads();
  }

  // ---- epilogue: write 3 channels x 4 rows
  float* outb = Out + (size_t)b * CC * HW + (size_t)y0 * WOUT + x;
#pragma unroll
  for (int c = 0; c < CC; ++c) {
#pragma unroll
    for (int t = 0; t < KY; ++t) {
      __builtin_nontemporal_store(acc[c][t], &outb[(size_t)c * HW + t * WOUT]);
    }
  }
}

extern "C" void kernel_launch(void* const* d_in, const int* in_sizes, int n_in,
                              void* d_out, int out_size, void* d_ws, size_t ws_size,
                              hipStream_t stream) {
  const float* In = (const float*)d_in[0];
  const float* Ver = (const float*)d_in[1];
  const float* Hor = (const float*)d_in[2];
  float* Out = (float*)d_out;

  dim3 grid(WOUT / TX, HOUT / KY, 4);
  sepconv_kernel<<<grid, dim3(TX, 1, 1), 0, stream>>>(In, Ver, Hor, Out);
}